// Round 11
// baseline (59.737 us; speedup 1.0000x reference)
//
#include <hip/hip_runtime.h>
#include <hip/hip_bf16.h>

#define VOCAB 128
#define HIDDEN 128

typedef float f32x4 __attribute__((ext_vector_type(4)));

// Block o computes column o of both tables; threads 0-127 (waves 0,1) do
//   T1[v][o] = sum_h emb[v][h]*W[o][h] + b[o],
// threads 128-255 (waves 2,3) do
//   T2[v][o] = sum_h emb[v][h]*W[o][128+h].
__global__ __launch_bounds__(256) void precompute_tables(
        const float* __restrict__ emb,
        const float* __restrict__ W,
        const float* __restrict__ b,
        float* __restrict__ T1,
        float* __restrict__ T2) {
    __shared__ float es[VOCAB * (HIDDEN + 1)];
    int t = threadIdx.x;
    int o = blockIdx.x;

    for (int i = 0; i < (VOCAB * HIDDEN) / (256 * 4); ++i) {
        int f = (i * 256 + t) * 4;
        f32x4 val = *reinterpret_cast<const f32x4*>(emb + f);
        int v = f >> 7;
        int h = f & 127;
        float* d = es + v * (HIDDEN + 1) + h;
        d[0] = val.x; d[1] = val.y; d[2] = val.z; d[3] = val.w;
    }
    __syncthreads();

    int v = t & 127;
    int which = t >> 7;                          // wave-uniform
    const float* wr = W + o * (2 * HIDDEN) + which * HIDDEN;
    const float* er = es + v * (HIDDEN + 1);
    float s = 0.f;
#pragma unroll 16
    for (int h = 0; h < HIDDEN; ++h)
        s += er[h] * wr[h];
    if (which == 0) T1[v * HIDDEN + o] = s + b[o];
    else            T2[v * HIDDEN + o] = s;
}

// Edge kernel, fully decoupled pipes:
//   - vector-memory pipe: ONLY nt-stores (fill-kernel profile, ~7 TB/s)
//   - LDS pipe (lgkmcnt):  2 x ds_read_b128 table reads per wave-iter
//   - scalar pipe (SQC):   edge + vocab index loads (wave-uniform)
// Wave = 2 consecutive edges; half-wave 0 -> e0, half-wave 1 -> e1.
// LDS: T1|T2 = 128 KB -> 1 block/CU @ 1024 thr = 16 waves/CU (optimum).
#define EDGE_GRID  256
#define EDGE_BLOCK 1024
#define TBL_FLOATS (2 * VOCAB * HIDDEN)   // 32768 floats = 128 KB

__global__ __launch_bounds__(EDGE_BLOCK) void edge_gather_add(
        const int* __restrict__ z,
        const int* __restrict__ src,
        const int* __restrict__ dst,
        const float* __restrict__ Tg,   // T1|T2 contiguous
        float* __restrict__ out,
        int E) {
    extern __shared__ float lds[];      // [0..16383]=T1, [16384..]=T2
    int t = threadIdx.x;

    // Stage both tables: 8192 f32x4, 1024 threads, 8 coalesced iters.
#pragma unroll
    for (int i = 0; i < TBL_FLOATS / (EDGE_BLOCK * 4); ++i) {
        int f = (i * EDGE_BLOCK + t) * 4;
        *reinterpret_cast<f32x4*>(lds + f) =
            *reinterpret_cast<const f32x4*>(Tg + f);
    }
    __syncthreads();

    const float* lT2 = lds + VOCAB * HIDDEN;
    int tid  = blockIdx.x * EDGE_BLOCK + t;
    int wid  = __builtin_amdgcn_readfirstlane(tid >> 6);  // uniform wave id
    int lane = t & 63;
    int q4   = (lane & 31) << 2;      // float offset within the 128-row
    int hi   = lane >> 5;             // 0: edge e0, 1: edge e1
    int estep = (EDGE_GRID * EDGE_BLOCK) >> 5;            // 8192 edges/sweep

    for (int e0 = wid * 2; e0 < E; e0 += estep) {
        int e1 = e0 + 1;
        if (e1 >= E) e1 = E - 1;      // scalar clamp (tail safety)
        // Scalar loads (SQC path): edge endpoints + vocab ids.
        int s0 = src[e0], s1 = src[e1];
        int d0 = dst[e0], d1 = dst[e1];
        int zs0 = z[s0], zs1 = z[s1];
        int zd0 = z[d0], zd1 = z[d1];
        // Per-lane select of this half-wave's vocab pair.
        int zs = hi ? zs1 : zs0;
        int zd = hi ? zd1 : zd0;
        f32x4 a = *reinterpret_cast<const f32x4*>(lds + zs * HIDDEN + q4);
        f32x4 c = *reinterpret_cast<const f32x4*>(lT2 + zd * HIDDEN + q4);
        f32x4 r = a + c;
        int eo = e0 + hi;
        if (eo < E)
            __builtin_nontemporal_store(r,
                reinterpret_cast<f32x4*>(out + (size_t)eo * HIDDEN + q4));
    }
}

extern "C" void kernel_launch(void* const* d_in, const int* in_sizes, int n_in,
                              void* d_out, int out_size, void* d_ws, size_t ws_size,
                              hipStream_t stream) {
    const int*   z    = (const int*)d_in[0];          // [N_NODES]
    const int*   ei   = (const int*)d_in[1];          // [2, E] row-major
    const float* emb  = (const float*)d_in[2];        // [128, 128]
    const float* W    = (const float*)d_in[3];        // [128, 256]
    const float* b    = (const float*)d_in[4];        // [128]
    float*       out  = (float*)d_out;                // [E, 128]

    int E = in_sizes[1] / 2;
    const int* src = ei;
    const int* dst = ei + E;

    float* T1 = (float*)d_ws;                         // 64 KB
    float* T2 = T1 + VOCAB * HIDDEN;                  // 64 KB (contiguous)

    precompute_tables<<<VOCAB, 256, 0, stream>>>(emb, W, b, T1, T2);

    hipFuncSetAttribute((const void*)edge_gather_add,
                        hipFuncAttributeMaxDynamicSharedMemorySize,
                        TBL_FLOATS * 4);
    edge_gather_add<<<EDGE_GRID, EDGE_BLOCK, TBL_FLOATS * 4, stream>>>(
        z, src, dst, T1, out, E);
}

// Round 12
// 55.004 us; speedup vs baseline: 1.0860x; 1.0860x over previous
//
#include <hip/hip_runtime.h>
#include <hip/hip_bf16.h>

#define VOCAB 128
#define HIDDEN 128

typedef float f32x4 __attribute__((ext_vector_type(4)));

// Block o computes column o of both tables; threads 0-127 (waves 0,1) do
//   T1[v][o] = sum_h emb[v][h]*W[o][h] + b[o],
// threads 128-255 (waves 2,3) do
//   T2[v][o] = sum_h emb[v][h]*W[o][128+h].
__global__ __launch_bounds__(256) void precompute_tables(
        const float* __restrict__ emb,
        const float* __restrict__ W,
        const float* __restrict__ b,
        float* __restrict__ T1,
        float* __restrict__ T2) {
    __shared__ float es[VOCAB * (HIDDEN + 1)];
    int t = threadIdx.x;
    int o = blockIdx.x;

    for (int i = 0; i < (VOCAB * HIDDEN) / (256 * 4); ++i) {
        int f = (i * 256 + t) * 4;
        f32x4 val = *reinterpret_cast<const f32x4*>(emb + f);
        int v = f >> 7;
        int h = f & 127;
        float* d = es + v * (HIDDEN + 1) + h;
        d[0] = val.x; d[1] = val.y; d[2] = val.z; d[3] = val.w;
    }
    __syncthreads();

    int v = t & 127;
    int which = t >> 7;                          // wave-uniform
    const float* wr = W + o * (2 * HIDDEN) + which * HIDDEN;
    const float* er = es + v * (HIDDEN + 1);
    float s = 0.f;
#pragma unroll 16
    for (int h = 0; h < HIDDEN; ++h)
        s += er[h] * wr[h];
    if (which == 0) T1[v * HIDDEN + o] = s + b[o];
    else            T2[v * HIDDEN + o] = s;
}

// Edge kernel (R10 structure + software pipeline).
// Wave = 2 consecutive edges/iter; indices on the SCALAR path (lgkmcnt),
// table rows via L1/L2 vector loads, output via nt-store.
// Pipeline: table loads for iter k+1 are issued BEFORE iter k's store, so
// the wait-for-loads at iter k+1 is vmcnt(1) (store stays outstanding) —
// store drain no longer gates the read chain. Indices fetched 2 ahead.
#define EDGE_GRID 1024
#define EDGE_BLOCK 256
#define ESTEP ((EDGE_GRID * EDGE_BLOCK) >> 5)   // 8192 edges per sweep

__global__ __launch_bounds__(EDGE_BLOCK) void edge_gather_add(
        const int* __restrict__ z,
        const int* __restrict__ src,
        const int* __restrict__ dst,
        const float* __restrict__ T1,
        const float* __restrict__ T2,
        float* __restrict__ out,
        int E) {
    int tid  = blockIdx.x * EDGE_BLOCK + threadIdx.x;
    int wid  = __builtin_amdgcn_readfirstlane(tid >> 6);  // uniform wave id
    int lane = threadIdx.x & 63;
    int q4   = (lane & 31) << 2;      // float offset within the 128-row
    int hi   = lane >> 5;             // 0: edge e0, 1: edge e1

    // Clamped wave-uniform index fetch (scalar path).
    auto fetch_idx = [&](int e, int& zs, int& zd) {
        int ea = e < E ? e : E - 1;
        int eb = e + 1 < E ? e + 1 : E - 1;
        int s0 = src[ea], s1 = src[eb];
        int d0 = dst[ea], d1 = dst[eb];
        int zs0 = z[s0], zs1 = z[s1];
        int zd0 = z[d0], zd1 = z[d1];
        zs = hi ? zs1 : zs0;
        zd = hi ? zd1 : zd0;
    };

    int e = wid * 2;
    if (e >= E) return;

    // Prologue: idx(j0) + rows(j0), idx(j1).
    int zsA, zdA, zsB, zdB;
    fetch_idx(e, zsA, zdA);
    f32x4 a = *reinterpret_cast<const f32x4*>(T1 + zsA * HIDDEN + q4);
    f32x4 c = *reinterpret_cast<const f32x4*>(T2 + zdA * HIDDEN + q4);
    fetch_idx(e + ESTEP, zsB, zdB);

    for (; e < E; e += ESTEP) {
        // Issue idx for j+2 (scalar, lgkmcnt — independent of vmcnt).
        int zsN, zdN;
        fetch_idx(e + 2 * ESTEP, zsN, zdN);
        // Issue table rows for j+1 BEFORE this iteration's store.
        f32x4 an = *reinterpret_cast<const f32x4*>(T1 + zsB * HIDDEN + q4);
        f32x4 cn = *reinterpret_cast<const f32x4*>(T2 + zdB * HIDDEN + q4);
        // Compute + nt-store iteration j (uses rows issued last iter).
        f32x4 r = a + c;
        int eo = e + hi;
        if (eo < E)
            __builtin_nontemporal_store(r,
                reinterpret_cast<f32x4*>(out + (size_t)eo * HIDDEN + q4));
        // Rotate pipeline registers.
        a = an; c = cn;
        zsB = zsN; zdB = zdN;
    }
}

extern "C" void kernel_launch(void* const* d_in, const int* in_sizes, int n_in,
                              void* d_out, int out_size, void* d_ws, size_t ws_size,
                              hipStream_t stream) {
    const int*   z    = (const int*)d_in[0];          // [N_NODES]
    const int*   ei   = (const int*)d_in[1];          // [2, E] row-major
    const float* emb  = (const float*)d_in[2];        // [128, 128]
    const float* W    = (const float*)d_in[3];        // [128, 256]
    const float* b    = (const float*)d_in[4];        // [128]
    float*       out  = (float*)d_out;                // [E, 128]

    int E = in_sizes[1] / 2;
    const int* src = ei;
    const int* dst = ei + E;

    float* T1 = (float*)d_ws;                         // 64 KB
    float* T2 = T1 + VOCAB * HIDDEN;                  // 64 KB

    precompute_tables<<<VOCAB, 256, 0, stream>>>(emb, W, b, T1, T2);

    edge_gather_add<<<EDGE_GRID, EDGE_BLOCK, 0, stream>>>(z, src, dst, T1, T2, out, E);
}

// Round 13
// 50.836 us; speedup vs baseline: 1.1751x; 1.0820x over previous
//
#include <hip/hip_runtime.h>
#include <hip/hip_bf16.h>

#define VOCAB 128
#define HIDDEN 128

typedef float f32x4 __attribute__((ext_vector_type(4)));

// Block o computes column o of both tables; threads 0-127 (waves 0,1) do
//   T1[v][o] = sum_h emb[v][h]*W[o][h] + b[o],
// threads 128-255 (waves 2,3) do
//   T2[v][o] = sum_h emb[v][h]*W[o][128+h].
__global__ __launch_bounds__(256) void precompute_tables(
        const float* __restrict__ emb,
        const float* __restrict__ W,
        const float* __restrict__ b,
        float* __restrict__ T1,
        float* __restrict__ T2) {
    __shared__ float es[VOCAB * (HIDDEN + 1)];
    int t = threadIdx.x;
    int o = blockIdx.x;

    for (int i = 0; i < (VOCAB * HIDDEN) / (256 * 4); ++i) {
        int f = (i * 256 + t) * 4;
        f32x4 val = *reinterpret_cast<const f32x4*>(emb + f);
        int v = f >> 7;
        int h = f & 127;
        float* d = es + v * (HIDDEN + 1) + h;
        d[0] = val.x; d[1] = val.y; d[2] = val.z; d[3] = val.w;
    }
    __syncthreads();

    int v = t & 127;
    int which = t >> 7;                          // wave-uniform
    const float* wr = W + o * (2 * HIDDEN) + which * HIDDEN;
    const float* er = es + v * (HIDDEN + 1);
    float s = 0.f;
#pragma unroll 16
    for (int h = 0; h < HIDDEN; ++h)
        s += er[h] * wr[h];
    if (which == 0) T1[v * HIDDEN + o] = s + b[o];
    else            T2[v * HIDDEN + o] = s;
}

// Edge kernel (R10 structure, 4 edges per wave-iteration).
// Indices on the SCALAR path: src[e0..3]/dst[e0..3] fetched as single
// uniform s_load_dwordx4 (half the dependent chains of R10 per byte);
// two INDEPENDENT nt-stores per iteration (adjacent 1 KB each -> 2 KB
// contiguous per wave-iter). Table rows via L1/L2 vector loads.
// Grid 1024x256 = 16 waves/CU (measured optimum).
#define EDGE_GRID 1024
#define EDGE_BLOCK 256
#define ESTEP4 ((EDGE_GRID * EDGE_BLOCK) >> 4)   // waves*4 = 16384 edges/sweep

__global__ __launch_bounds__(EDGE_BLOCK) void edge_gather_add(
        const int* __restrict__ z,
        const int* __restrict__ src,
        const int* __restrict__ dst,
        const float* __restrict__ T1,
        const float* __restrict__ T2,
        float* __restrict__ out,
        int E) {
    int tid  = blockIdx.x * EDGE_BLOCK + threadIdx.x;
    int wid  = __builtin_amdgcn_readfirstlane(tid >> 6);  // uniform wave id
    int lane = threadIdx.x & 63;
    int q4   = (lane & 31) << 2;      // float offset within the 128-row
    int hi   = lane >> 5;             // edge parity within each pair

    for (int e0 = wid * 4; e0 < E; e0 += ESTEP4) {
        int zs0, zs1, zs2, zs3, zd0, zd1, zd2, zd3;
        if (e0 + 3 < E) {
            // Uniform batched loads: one s_load_dwordx4 each (16B-aligned:
            // e0 % 4 == 0).
            int4 sv = *reinterpret_cast<const int4*>(src + e0);
            int4 dv = *reinterpret_cast<const int4*>(dst + e0);
            zs0 = z[sv.x]; zs1 = z[sv.y]; zs2 = z[sv.z]; zs3 = z[sv.w];
            zd0 = z[dv.x]; zd1 = z[dv.y]; zd2 = z[dv.z]; zd3 = z[dv.w];
        } else {
            int ea = e0, eb = e0 + 1 < E ? e0 + 1 : E - 1;
            int ec = e0 + 2 < E ? e0 + 2 : E - 1;
            int ed = e0 + 3 < E ? e0 + 3 : E - 1;
            zs0 = z[src[ea]]; zs1 = z[src[eb]]; zs2 = z[src[ec]]; zs3 = z[src[ed]];
            zd0 = z[dst[ea]]; zd1 = z[dst[eb]]; zd2 = z[dst[ec]]; zd3 = z[dst[ed]];
        }
        // Per-lane select of this half-wave's vocab pair, both edge-pairs.
        int zsA = hi ? zs1 : zs0, zdA = hi ? zd1 : zd0;
        int zsB = hi ? zs3 : zs2, zdB = hi ? zd3 : zd2;
        f32x4 aA = *reinterpret_cast<const f32x4*>(T1 + zsA * HIDDEN + q4);
        f32x4 cA = *reinterpret_cast<const f32x4*>(T2 + zdA * HIDDEN + q4);
        f32x4 aB = *reinterpret_cast<const f32x4*>(T1 + zsB * HIDDEN + q4);
        f32x4 cB = *reinterpret_cast<const f32x4*>(T2 + zdB * HIDDEN + q4);
        f32x4 rA = aA + cA;
        f32x4 rB = aB + cB;
        int eoA = e0 + hi;
        int eoB = e0 + 2 + hi;
        if (eoA < E)
            __builtin_nontemporal_store(rA,
                reinterpret_cast<f32x4*>(out + (size_t)eoA * HIDDEN + q4));
        if (eoB < E)
            __builtin_nontemporal_store(rB,
                reinterpret_cast<f32x4*>(out + (size_t)eoB * HIDDEN + q4));
    }
}

extern "C" void kernel_launch(void* const* d_in, const int* in_sizes, int n_in,
                              void* d_out, int out_size, void* d_ws, size_t ws_size,
                              hipStream_t stream) {
    const int*   z    = (const int*)d_in[0];          // [N_NODES]
    const int*   ei   = (const int*)d_in[1];          // [2, E] row-major
    const float* emb  = (const float*)d_in[2];        // [128, 128]
    const float* W    = (const float*)d_in[3];        // [128, 256]
    const float* b    = (const float*)d_in[4];        // [128]
    float*       out  = (float*)d_out;                // [E, 128]

    int E = in_sizes[1] / 2;
    const int* src = ei;
    const int* dst = ei + E;

    float* T1 = (float*)d_ws;                         // 64 KB
    float* T2 = T1 + VOCAB * HIDDEN;                  // 64 KB

    precompute_tables<<<VOCAB, 256, 0, stream>>>(emb, W, b, T1, T2);

    edge_gather_add<<<EDGE_GRID, EDGE_BLOCK, 0, stream>>>(z, src, dst, T1, T2, out, E);
}

// Round 14
// 49.860 us; speedup vs baseline: 1.1981x; 1.0196x over previous
//
#include <hip/hip_runtime.h>
#include <hip/hip_bf16.h>

#define VOCAB 128
#define HIDDEN 128

typedef float f32x4 __attribute__((ext_vector_type(4)));

// Block o computes column o of both tables; threads 0-127 (waves 0,1) do
//   T1[v][o] = sum_h emb[v][h]*W[o][h] + b[o],
// threads 128-255 (waves 2,3) do
//   T2[v][o] = sum_h emb[v][h]*W[o][128+h].
__global__ __launch_bounds__(256) void precompute_tables(
        const float* __restrict__ emb,
        const float* __restrict__ W,
        const float* __restrict__ b,
        float* __restrict__ T1,
        float* __restrict__ T2) {
    __shared__ float es[VOCAB * (HIDDEN + 1)];
    int t = threadIdx.x;
    int o = blockIdx.x;

    for (int i = 0; i < (VOCAB * HIDDEN) / (256 * 4); ++i) {
        int f = (i * 256 + t) * 4;
        f32x4 val = *reinterpret_cast<const f32x4*>(emb + f);
        int v = f >> 7;
        int h = f & 127;
        float* d = es + v * (HIDDEN + 1) + h;
        d[0] = val.x; d[1] = val.y; d[2] = val.z; d[3] = val.w;
    }
    __syncthreads();

    int v = t & 127;
    int which = t >> 7;                          // wave-uniform
    const float* wr = W + o * (2 * HIDDEN) + which * HIDDEN;
    const float* er = es + v * (HIDDEN + 1);
    float s = 0.f;
#pragma unroll 16
    for (int h = 0; h < HIDDEN; ++h)
        s += er[h] * wr[h];
    if (which == 0) T1[v * HIDDEN + o] = s + b[o];
    else            T2[v * HIDDEN + o] = s;
}

// Edge kernel (R10 — measured best, 48.9 us):
// one wave = 2 consecutive edges per iteration.
// Edge/vocab indices are wave-uniform -> fetched via the SCALAR path
// (s_load, lgkmcnt) by deriving the wave id with readfirstlane. Vector
// path per iteration: 2 table loads (L1/L2) + 1 nt-store (2 KB contiguous
// per wave pair of edges). Grid 1024x256 = 16 waves/CU (measured optimum:
// 512->66us, 1024->48.9us, 2048->53us).
#define EDGE_GRID 1024
#define EDGE_BLOCK 256

__global__ __launch_bounds__(EDGE_BLOCK) void edge_gather_add(
        const int* __restrict__ z,
        const int* __restrict__ src,
        const int* __restrict__ dst,
        const float* __restrict__ T1,
        const float* __restrict__ T2,
        float* __restrict__ out,
        int E) {
    int tid  = blockIdx.x * EDGE_BLOCK + threadIdx.x;
    int wid  = __builtin_amdgcn_readfirstlane(tid >> 6);  // uniform wave id
    int lane = threadIdx.x & 63;
    int q4   = (lane & 31) << 2;      // float offset within the 128-row
    int hi   = lane >> 5;             // 0: edge e0, 1: edge e1
    int estep = (EDGE_GRID * EDGE_BLOCK) >> 5;            // 16384/2 edges/sweep

    for (int e0 = wid * 2; e0 < E; e0 += estep) {
        int e1 = e0 + 1;
        if (e1 >= E) e1 = E - 1;      // scalar clamp (tail safety)
        // Scalar loads (SQC path): edge endpoints + vocab ids.
        int s0 = src[e0], s1 = src[e1];
        int d0 = dst[e0], d1 = dst[e1];
        int zs0 = z[s0], zs1 = z[s1];
        int zd0 = z[d0], zd1 = z[d1];
        // Per-lane select of this half-wave's vocab pair.
        int zs = hi ? zs1 : zs0;
        int zd = hi ? zd1 : zd0;
        f32x4 a = *reinterpret_cast<const f32x4*>(T1 + zs * HIDDEN + q4);
        f32x4 c = *reinterpret_cast<const f32x4*>(T2 + zd * HIDDEN + q4);
        f32x4 r = a + c;
        int eo = e0 + hi;
        if (eo < E)
            __builtin_nontemporal_store(r,
                reinterpret_cast<f32x4*>(out + (size_t)eo * HIDDEN + q4));
    }
}

extern "C" void kernel_launch(void* const* d_in, const int* in_sizes, int n_in,
                              void* d_out, int out_size, void* d_ws, size_t ws_size,
                              hipStream_t stream) {
    const int*   z    = (const int*)d_in[0];          // [N_NODES]
    const int*   ei   = (const int*)d_in[1];          // [2, E] row-major
    const float* emb  = (const float*)d_in[2];        // [128, 128]
    const float* W    = (const float*)d_in[3];        // [128, 256]
    const float* b    = (const float*)d_in[4];        // [128]
    float*       out  = (float*)d_out;                // [E, 128]

    int E = in_sizes[1] / 2;
    const int* src = ei;
    const int* dst = ei + E;

    float* T1 = (float*)d_ws;                         // 64 KB
    float* T2 = T1 + VOCAB * HIDDEN;                  // 64 KB

    precompute_tables<<<VOCAB, 256, 0, stream>>>(emb, W, b, T1, T2);

    edge_gather_add<<<EDGE_GRID, EDGE_BLOCK, 0, stream>>>(z, src, dst, T1, T2, out, E);
}